// Round 21
// baseline (150.266 us; speedup 1.0000x reference)
//
#include <hip/hip_runtime.h>

// All tensors float32. Math structure exploited:
//  - softmax over axis of size 1 == 1.0 -> attn all-ones, Wa/ba dead.
//  - weighted = row-sum of tanh(agg), broadcast over COLUMNS (N==D quirk).
//  - lig_p = nf@Wl.T + const  ->  x0[h,i,j] = PL[i,h] + PR[j,h] + c[h]
//  - conv1 is LINEAR in rank-structured x0: y1_pre = U[xc][y] + V[yc][x] + K'.
//  - ROUND-21 (instrumentation): pp's ~44us residual survived THREE disjoint
//    structural rewrites (LDS pipeline / Ws fix / barrier-free) -> the
//    attribution is wrong, not the structure. pp split into 3 separate
//    dispatches with identical bodies (pguv 32 blocks, w2pack 1, cveck 1) so
//    per-piece counters + gnn all become visible in the top-5. gnn/conv
//    byte-identical to round 18/20.

typedef _Float16 half8 __attribute__((ext_vector_type(8)));
typedef _Float16 half4 __attribute__((ext_vector_type(4)));
typedef float    f32x4 __attribute__((ext_vector_type(4)));

__device__ __forceinline__ short f2h_bits(float f){
    _Float16 h = (_Float16)f;          // RNE
    return __builtin_bit_cast(short, h);
}
__device__ __forceinline__ half8 pack2(const float4& x, const float4& y){
    half8 r;
    r[0] = (_Float16)x.x; r[1] = (_Float16)x.y;
    r[2] = (_Float16)x.z; r[3] = (_Float16)x.w;
    r[4] = (_Float16)y.x; r[5] = (_Float16)y.y;
    r[6] = (_Float16)y.z; r[7] = (_Float16)y.w;
    return r;
}
__device__ __forceinline__ float tanh_fast(float x){
    float e = __expf(2.f * x);
    return 1.f - 2.f / (e + 1.f);
}

// ci-block swizzle (round-4 verified layout)
#define SWZ(c) ((((c) >> 1) & 3) << 3)

// ---------------------------------------------------------------------------
// K1 (MFMA): gnn, BM=128/BN=64/BK=64, 512 thr, depth-2 reg prefetch.
// grid (8,16,2). (round-15..20 verbatim)
// ---------------------------------------------------------------------------
#define GNN_LOAD(AV, BV, KBN) {                                              \
    const int kbn_ = (KBN) & 2047;                                           \
    const float* Asrc_ = (kbn_ < 1024) ? A0 : A1;                            \
    const float* Bsrc_ = (kbn_ < 1024) ? Wn : We;                            \
    const int kk_ = kbn_ & 1023;                                             \
    const float* ap_ = Asrc_ + (size_t)(j0 + arow) * 1024 + kk_ + akc;       \
    const float* bp_ = Bsrc_ + (size_t)(d0 + brow) * 1024 + kk_ + bkc;       \
    AV[0] = *reinterpret_cast<const float4*>(ap_);                           \
    AV[1] = *reinterpret_cast<const float4*>(ap_ + 4);                       \
    AV[2] = *reinterpret_cast<const float4*>(ap_ + 8);                       \
    AV[3] = *reinterpret_cast<const float4*>(ap_ + 12);                      \
    BV[0] = *reinterpret_cast<const float4*>(bp_);                           \
    BV[1] = *reinterpret_cast<const float4*>(bp_ + 4);                       \
}

#define GNN_STAGE(AV, BV) {                                                  \
    const int ga_ = (t & 3) * 2;                                             \
    const int sa_ = arow & 7;                                                \
    *reinterpret_cast<half8*>(&As[arow * 64 + ((ga_    ) ^ sa_) * 8]) = pack2(AV[0], AV[1]); \
    *reinterpret_cast<half8*>(&As[arow * 64 + ((ga_ + 1) ^ sa_) * 8]) = pack2(AV[2], AV[3]); \
    *reinterpret_cast<half8*>(&Bs[brow * 64 + ((t & 7) ^ (brow & 7)) * 8]) = pack2(BV[0], BV[1]); \
}

#define GNN_MFMA() {                                                         \
    _Pragma("unroll")                                                        \
    for (int ks = 0; ks < 2; ++ks){                                          \
        half8 Af[2], Bf[2];                                                  \
        _Pragma("unroll")                                                    \
        for (int m = 0; m < 2; ++m){                                         \
            int row = wm * 32 + m * 16 + lr;                                 \
            int g   = ((ks * 4 + lg) ^ (row & 7)) * 8;                       \
            Af[m] = *reinterpret_cast<const half8*>(&As[row * 64 + g]);      \
        }                                                                    \
        _Pragma("unroll")                                                    \
        for (int n = 0; n < 2; ++n){                                         \
            int col = wn * 32 + n * 16 + lr;                                 \
            int g   = ((ks * 4 + lg) ^ (col & 7)) * 8;                       \
            Bf[n] = *reinterpret_cast<const half8*>(&Bs[col * 64 + g]);      \
        }                                                                    \
        _Pragma("unroll")                                                    \
        for (int m = 0; m < 2; ++m)                                          \
            _Pragma("unroll")                                                \
            for (int n = 0; n < 2; ++n)                                      \
                acc[m][n] = __builtin_amdgcn_mfma_f32_16x16x32_f16(          \
                    Af[m], Bf[n], acc[m][n], 0, 0, 0);                       \
    }                                                                        \
}

__global__ __launch_bounds__(512) void gnn_kernel(
    const float* __restrict__ lig_nf, const float* __restrict__ lig_ef,
    const float* __restrict__ rec_nf, const float* __restrict__ rec_ef,
    const float* __restrict__ Wn, const float* __restrict__ We,
    const float* __restrict__ bn, const float* __restrict__ be,
    float* __restrict__ part)   // [2][16][1024]
{
    __shared__ __attribute__((aligned(16))) short As[128 * 64];
    __shared__ __attribute__((aligned(16))) short Bs[64 * 64];
    __shared__ float red[128][2];

    const int t  = threadIdx.x;
    const int cx = blockIdx.z;
    const float* A0 = cx ? rec_nf : lig_nf;
    const float* A1 = cx ? rec_ef : lig_ef;
    const int j0 = blockIdx.x * 128;
    const int d0 = blockIdx.y * 64;

    const int wid  = t >> 6;
    const int wm   = wid >> 1;
    const int wn   = wid & 1;
    const int lane = t & 63;
    const int lr   = lane & 15;
    const int lg   = lane >> 4;

    f32x4 acc[2][2];
    #pragma unroll
    for (int m = 0; m < 2; ++m)
        #pragma unroll
        for (int n = 0; n < 2; ++n)
            acc[m][n] = (f32x4){0.f, 0.f, 0.f, 0.f};

    const int arow = t >> 2;
    const int akc  = (t & 3) * 16;
    const int brow = t >> 3;
    const int bkc  = (t & 7) * 8;

    float4 avA[4], bvA[2], avB[4], bvB[2];
    GNN_LOAD(avA, bvA, 0);
    GNN_LOAD(avB, bvB, 64);

    for (int kb = 0; kb < 2048; kb += 128){
        __syncthreads();
        GNN_STAGE(avA, bvA);
        GNN_LOAD(avA, bvA, kb + 128);
        __syncthreads();
        GNN_MFMA();
        __syncthreads();
        GNN_STAGE(avB, bvB);
        GNN_LOAD(avB, bvB, kb + 192);
        __syncthreads();
        GNN_MFMA();
    }

    float rowsum[2][4];
    #pragma unroll
    for (int m = 0; m < 2; ++m)
        #pragma unroll
        for (int jj = 0; jj < 4; ++jj) rowsum[m][jj] = 0.f;
    #pragma unroll
    for (int n = 0; n < 2; ++n){
        int d = d0 + wn * 32 + n * 16 + lr;
        float bias = bn[d] + be[d];
        #pragma unroll
        for (int m = 0; m < 2; ++m)
            #pragma unroll
            for (int jj = 0; jj < 4; ++jj)
                rowsum[m][jj] += tanh_fast(acc[m][n][jj] + bias);
    }
    #pragma unroll
    for (int mask = 1; mask < 16; mask <<= 1)
        #pragma unroll
        for (int m = 0; m < 2; ++m)
            #pragma unroll
            for (int jj = 0; jj < 4; ++jj)
                rowsum[m][jj] += __shfl_xor(rowsum[m][jj], mask);
    __syncthreads();
    if (lr == 0){
        #pragma unroll
        for (int m = 0; m < 2; ++m)
            #pragma unroll
            for (int jj = 0; jj < 4; ++jj)
                red[wm * 32 + m * 16 + lg * 4 + jj][wn] = rowsum[m][jj];
    }
    __syncthreads();
    if (t < 128)
        part[(size_t)cx * 16384 + (size_t)blockIdx.y * 1024 + j0 + t]
            = red[t][0] + red[t][1];
}

// ---------------------------------------------------------------------------
// K2a: pguv_kernel. grid 32 x 512 thr. Barrier-free P GEMM (per-lane
// fragment loads from global), Ws from contiguous tap loads, one barrier,
// uv MFMA. (round-20 role<32 body, standalone)
// ---------------------------------------------------------------------------
__global__ __launch_bounds__(512) void pguv_kernel(
    const float* __restrict__ lig_nf, const float* __restrict__ rec_nf,
    const float* __restrict__ W_hopi, const float* __restrict__ w1,
    short* __restrict__ U16, short* __restrict__ V16)
{
    __shared__ __attribute__((aligned(16))) short Pz[80 * 40];
    __shared__ __attribute__((aligned(16))) short Ws[3 * 32 * 104];

    const int t = threadIdx.x;
    const int cx = blockIdx.x >> 4;
    const int r0 = (blockIdx.x & 15) * 64;
    const float* nf = cx ? rec_nf : lig_nf;
    const float* W  = W_hopi + (cx ? 1024 : 0);
    short* O = cx ? V16 : U16;

    const int wid = t >> 6;
    const int lane = t & 63;
    const int lr = lane & 15;
    const int lg = lane >> 4;

    // ---- barrier-free P GEMM: waves 0-4, 16 rows each (80 incl halo) ----
    f32x4 pacc[2];
    pacc[0] = (f32x4){0.f, 0.f, 0.f, 0.f};
    pacc[1] = (f32x4){0.f, 0.f, 0.f, 0.f};

    if (wid < 5){
        const int lrow = wid * 16 + lr;          // 0..79
        const int grow = r0 - 8 + lrow;
        const bool ok = (unsigned)grow < 1024u;
        const float* ap  = nf + (size_t)(ok ? grow : 0) * 1024 + lg * 8;
        const float* b0  = W + (size_t)lr * 2048 + lg * 8;
        const float* b1p = W + (size_t)(16 + lr) * 2048 + lg * 8;

        #pragma unroll 4
        for (int kb = 0; kb < 1024; kb += 32){
            float4 a0 = make_float4(0.f, 0.f, 0.f, 0.f);
            float4 a1 = a0;
            if (ok){
                a0 = *reinterpret_cast<const float4*>(ap + kb);
                a1 = *reinterpret_cast<const float4*>(ap + kb + 4);
            }
            half8 Af = pack2(a0, a1);
            half8 B0 = pack2(*reinterpret_cast<const float4*>(b0 + kb),
                             *reinterpret_cast<const float4*>(b0 + kb + 4));
            half8 B1 = pack2(*reinterpret_cast<const float4*>(b1p + kb),
                             *reinterpret_cast<const float4*>(b1p + kb + 4));
            pacc[0] = __builtin_amdgcn_mfma_f32_16x16x32_f16(Af, B0, pacc[0], 0, 0, 0);
            pacc[1] = __builtin_amdgcn_mfma_f32_16x16x32_f16(Af, B1, pacc[1], 0, 0, 0);
        }
        #pragma unroll
        for (int n = 0; n < 2; ++n)
            #pragma unroll
            for (int jj = 0; jj < 4; ++jj){
                int rowl = wid * 16 + lg * 4 + jj;
                Pz[rowl * 40 + n * 16 + lr] = f2h_bits(pacc[n][jj]);
            }
    }

    // ---- Ws from contiguous tap loads ----
    #pragma unroll
    for (int q = 0; q < 2; ++q){
        int pr = t * 2 + q;              // (co,ci) pair 0..1023
        int co = pr >> 5;
        int ci = pr & 31;
        const float* wp = w1 + co * 288 + ci * 9;
        float tap[9];
        #pragma unroll
        for (int e = 0; e < 9; ++e) tap[e] = wp[e];
        #pragma unroll
        for (int d = 0; d < 3; ++d){
            float ta, tb, tc;
            if (cx == 0){ ta = tap[d * 3 + 0]; tb = tap[d * 3 + 1]; tc = tap[d * 3 + 2]; }
            else        { ta = tap[0 + d];     tb = tap[3 + d];     tc = tap[6 + d]; }
            Ws[(0 * 32 + co) * 104 + d * 32 + ci] = f2h_bits(ta + tb + tc);
            Ws[(1 * 32 + co) * 104 + d * 32 + ci] = f2h_bits(tb + tc);
            Ws[(2 * 32 + co) * 104 + d * 32 + ci] = f2h_bits(ta + tb);
        }
    }
    __syncthreads();

    // ---- uv GEMM (waves 0-3): 64 rows x 32 co x K=96 ----
    if (wid < 4){
        f32x4 uacc[3][2];
        #pragma unroll
        for (int cs = 0; cs < 3; ++cs)
            #pragma unroll
            for (int n = 0; n < 2; ++n)
                uacc[cs][n] = (f32x4){0.f, 0.f, 0.f, 0.f};
        #pragma unroll
        for (int d = 0; d < 3; ++d){
            int ar = wid * 16 + lr;
            half8 Ap = *reinterpret_cast<const half8*>(
                &Pz[(7 + ar + d) * 40 + lg * 8]);
            #pragma unroll
            for (int cs = 0; cs < 3; ++cs)
                #pragma unroll
                for (int n = 0; n < 2; ++n){
                    half8 Bp = *reinterpret_cast<const half8*>(
                        &Ws[(cs * 32 + n * 16 + lr) * 104 + d * 32 + lg * 8]);
                    uacc[cs][n] = __builtin_amdgcn_mfma_f32_16x16x32_f16(
                        Ap, Bp, uacc[cs][n], 0, 0, 0);
                }
        }
        #pragma unroll
        for (int cs = 0; cs < 3; ++cs)
            #pragma unroll
            for (int n = 0; n < 2; ++n)
                #pragma unroll
                for (int jj = 0; jj < 4; ++jj){
                    int grow = r0 + wid * 16 + lg * 4 + jj;
                    O[((size_t)(cs << 10) + grow) * 32 + n * 16 + lr]
                        = f2h_bits(uacc[cs][n][jj]);
                }
    }
}

// ---------------------------------------------------------------------------
// K2b: w2pack_kernel. 1 block x 512.
// ---------------------------------------------------------------------------
__global__ __launch_bounds__(512) void w2pack_kernel(
    const float* __restrict__ w2, short* __restrict__ w2f16)
{
    const int t = threadIdx.x;
    #pragma unroll
    for (int q = 0; q < 18; ++q){
        int e = t + q * 512;
        int co  = e / 288;
        int rem = e - co * 288;
        int ci  = rem / 9;
        int tap = rem - ci * 9;
        w2f16[(tap * 32 + co) * 32 + (ci ^ SWZ(co))] = f2h_bits(w2[e]);
    }
}

// ---------------------------------------------------------------------------
// K2c: cveck_kernel. 1 block x 512. (round-18 role-32 body, standalone)
// ---------------------------------------------------------------------------
__global__ __launch_bounds__(512) void cveck_kernel(
    const float* __restrict__ W_hopi, const float* __restrict__ b_hopi,
    const float* __restrict__ w1, const float* __restrict__ b1,
    const float* __restrict__ part, float* __restrict__ Kp)
{
    __shared__ float ws_l[1024];
    __shared__ float ws_r[1024];
    __shared__ float red[512];
    __shared__ float cvs[32];
    __shared__ float w1s[9216];

    const int t = threadIdx.x;
    #pragma unroll
    for (int q = 0; q < 5; ++q){
        int i4 = t + q * 512;
        if (i4 < 2304)
            *reinterpret_cast<float4*>(&w1s[i4 * 4]) =
                *reinterpret_cast<const float4*>(w1 + i4 * 4);
    }
    for (int j = t; j < 1024; j += 512){
        float sl = 0.f, sr = 0.f;
        #pragma unroll
        for (int b = 0; b < 16; ++b){
            sl += part[b * 1024 + j];
            sr += part[16384 + b * 1024 + j];
        }
        ws_l[j] = sl; ws_r[j] = sr;
    }
    __syncthreads();
    {
        const int h = t & 31;
        const int seg = t >> 5;
        const float* wl = W_hopi + (size_t)h * 2048 + seg * 64;
        const float* wr = wl + 1024;
        float s = 0.f;
        #pragma unroll 8
        for (int j = 0; j < 64; j += 4){
            float4 a = *reinterpret_cast<const float4*>(wl + j);
            float4 b = *reinterpret_cast<const float4*>(wr + j);
            const float* l = &ws_l[seg * 64 + j];
            const float* r = &ws_r[seg * 64 + j];
            s = fmaf(l[0], a.x, s); s = fmaf(l[1], a.y, s);
            s = fmaf(l[2], a.z, s); s = fmaf(l[3], a.w, s);
            s = fmaf(r[0], b.x, s); s = fmaf(r[1], b.y, s);
            s = fmaf(r[2], b.z, s); s = fmaf(r[3], b.w, s);
        }
        red[t] = s;
    }
    __syncthreads();
    if (t < 32){
        float tot = b_hopi[t];
        #pragma unroll
        for (int g = 0; g < 16; ++g) tot += red[g * 32 + t];
        cvs[t] = tot;
    }
    __syncthreads();
    for (int e = t; e < 288; e += 512){
        int co  = e & 31;
        int cse = e >> 5;
        int yc  = cse / 3, xc = cse - yc * 3;
        float sum = b1[co];
        for (int ci = 0; ci < 32; ++ci){
            const float* wp = &w1s[co * 288 + ci * 9];
            float t00 = wp[0], t01 = wp[1], t02 = wp[2];
            float t10 = wp[3], t11 = wp[4], t12 = wp[5];
            float t20 = wp[6], t21 = wp[7], t22 = wp[8];
            float r0, r1, r2;
            if (xc == 0){ r0 = t00+t01+t02; r1 = t10+t11+t12; r2 = t20+t21+t22; }
            else if (xc == 1){ r0 = t01+t02; r1 = t11+t12; r2 = t21+t22; }
            else { r0 = t00+t01; r1 = t10+t11; r2 = t20+t21; }
            float wsum = (yc == 0) ? (r0+r1+r2) : ((yc == 1) ? (r1+r2) : (r0+r1));
            sum = fmaf(cvs[ci], wsum, sum);
        }
        Kp[cse * 32 + co] = sum;
    }
}

// ---------------------------------------------------------------------------
// K3: stage ys = relu(U+V+K') (interior fast path in packed f16), wB by uint4
// copy of prepacked w2f16, then conv2+relu+conv3 on f16 MFMA. LDS = 39,168 B.
// block 512, grid 64x64. (round-16 verbatim -- best measured conv, 46.0us)
// ---------------------------------------------------------------------------
__global__ __launch_bounds__(512) void conv_kernel(
    const short* __restrict__ U16, const short* __restrict__ V16,
    const float* __restrict__ Kp, const short* __restrict__ w2f16,
    const float* __restrict__ b2,
    const float* __restrict__ w3, const float* __restrict__ b3,
    float* __restrict__ outp)
{
    __shared__ __attribute__((aligned(16))) short ys[18 * 18 * 32];
    __shared__ __attribute__((aligned(16))) short wB[9 * 32 * 32];

    const int t    = threadIdx.x;
    const int oy0  = blockIdx.y * 16;
    const int ox0  = blockIdx.x * 16;
    const int wid  = t >> 6;
    const int lane = t & 63;
    const int lr   = lane & 15;
    const int lg   = lane >> 4;

    {
        const uint4* src = reinterpret_cast<const uint4*>(w2f16);
        uint4* dst = reinterpret_cast<uint4*>(wB);
        #pragma unroll
        for (int e = t; e < 1152; e += 512)
            dst[e] = src[e];
    }
    const bool interior = (blockIdx.x >= 1) & (blockIdx.x <= 62) &
                          (blockIdx.y >= 1) & (blockIdx.y <= 62);
    if (interior){
        const int cp = (t & 7) * 4;
        half4 k00;
        {
            float4 kf = *reinterpret_cast<const float4*>(&Kp[cp]);
            k00[0] = (_Float16)kf.x; k00[1] = (_Float16)kf.y;
            k00[2] = (_Float16)kf.z; k00[3] = (_Float16)kf.w;
        }
        #pragma unroll
        for (int pass = 0; pass < 6; ++pass){
            int idx = t + pass * 512;
            if (idx < 2592){
                int po  = idx >> 3;
                int ryo = po / 18;
                int rxo = po - ryo * 18;
                int gy = oy0 - 1 + ryo, gx = ox0 - 1 + rxo;
                half4 u = *reinterpret_cast<const half4*>(&U16[gy * 32 + cp]);
                half4 v = *reinterpret_cast<const half4*>(&V16[gx * 32 + cp]);
                half4 r = u + v + k00;
                #pragma unroll
                for (int e = 0; e < 4; ++e)
                    r[e] = r[e] > (_Float16)0.f ? r[e] : (_Float16)0.f;
                *reinterpret_cast<half4*>(&ys[po * 32 + (cp ^ SWZ(rxo))]) = r;
            }
        }
    } else {
        #pragma unroll
        for (int pass = 0; pass < 6; ++pass){
            int idx = t + pass * 512;
            if (idx < 2592){
                int po  = idx >> 3;
                int cp  = (idx & 7) * 4;
                int ryo = po / 18;
                int rxo = po - ryo * 18;
                int gy = oy0 - 1 + ryo, gx = ox0 - 1 + rxo;
                half4 h = {(_Float16)0.f, (_Float16)0.f, (_Float16)0.f, (_Float16)0.f};
                if ((unsigned)gy < 1024u && (unsigned)gx < 1024u){
                    int yc = (gy == 0) ? 1 : ((gy == 1023) ? 2 : 0);
                    int xc = (gx == 0) ? 1 : ((gx == 1023) ? 2 : 0);
                    half4 u = *reinterpret_cast<const half4*>(
                        &U16[((size_t)(xc << 10) + gy) * 32 + cp]);
                    half4 v = *reinterpret_cast<const half4*>(
                        &V16[((size_t)(yc << 10) + gx) * 32 + cp]);
                    float4 k = *reinterpret_cast<const float4*>(&Kp[(yc * 3 + xc) * 32 + cp]);
                    h[0] = (_Float16)fmaxf((float)u[0] + (float)v[0] + k.x, 0.f);
                    h[1] = (_Float16)fmaxf((float)u[1] + (float)v[1] + k.y, 0.f);
                    h[2] = (_Float16)fmaxf((float)u[2] + (float)v[2] + k.z, 0.f);
                    h[3] = (_Float16)fmaxf((float)u[3] + (float)v[3] + k.w, 0.f);
                }
                *reinterpret_cast<half4*>(&ys[po * 32 + (cp ^ SWZ(rxo))]) = h;
            }
        }
    }
    __syncthreads();

    {
        half8 Bf[2][9];
        float bias[2], w3v[2];
        #pragma unroll
        for (int n = 0; n < 2; ++n){
            int co = n * 16 + lr;
            bias[n] = b2[co];
            w3v[n]  = w3[co];
            #pragma unroll
            for (int tap = 0; tap < 9; ++tap)
                Bf[n][tap] = *reinterpret_cast<const half8*>(
                    &wB[(tap * 32 + co) * 32 + ((lg * 8) ^ SWZ(co))]);
        }
        const float b3v = b3[0];
        for (int s = wid; s < 16; s += 8){
            int p  = s * 16 + lr;
            int ry = p >> 4;
            int rx = p & 15;
            f32x4 acc0 = {0.f, 0.f, 0.f, 0.f};
            f32x4 acc1 = {0.f, 0.f, 0.f, 0.f};
            #pragma unroll
            for (int tap = 0; tap < 9; ++tap){
                const int dy = tap / 3, dx = tap - (tap / 3) * 3;
                int pix = (ry + dy) * 18 + rx + dx;
                half8 A = *reinterpret_cast<const half8*>(
                    &ys[pix * 32 + ((lg * 8) ^ SWZ(rx + dx))]);
                acc0 = __builtin_amdgcn_mfma_f32_16x16x32_f16(A, Bf[0][tap], acc0, 0, 0, 0);
                acc1 = __builtin_amdgcn_mfma_f32_16x16x32_f16(A, Bf[1][tap], acc1, 0, 0, 0);
            }
            float part[4];
            #pragma unroll
            for (int j = 0; j < 4; ++j)
                part[j] = w3v[0] * fmaxf(acc0[j] + bias[0], 0.f)
                        + w3v[1] * fmaxf(acc1[j] + bias[1], 0.f);
            #pragma unroll
            for (int m = 1; m < 16; m <<= 1)
                #pragma unroll
                for (int j = 0; j < 4; ++j)
                    part[j] += __shfl_xor(part[j], m);
            if (lr == 0){
                float4 o = make_float4(part[0] + b3v, part[1] + b3v,
                                       part[2] + b3v, part[3] + b3v);
                *reinterpret_cast<float4*>(outp + (size_t)(oy0 + s) * 1024 + ox0 + lg * 4) = o;
            }
        }
    }
}

// ---------------------------------------------------------------------------
extern "C" void kernel_launch(void* const* d_in, const int* in_sizes, int n_in,
                              void* d_out, int out_size, void* d_ws, size_t ws_size,
                              hipStream_t stream)
{
    const float* lig_nf = (const float*)d_in[0];
    const float* lig_ef = (const float*)d_in[1];
    const float* rec_nf = (const float*)d_in[3];
    const float* rec_ef = (const float*)d_in[4];
    const float* Wn     = (const float*)d_in[6];
    const float* bn     = (const float*)d_in[7];
    const float* We     = (const float*)d_in[8];
    const float* be     = (const float*)d_in[9];
    const float* W_hopi = (const float*)d_in[12];
    const float* b_hopi = (const float*)d_in[13];
    const float* w1     = (const float*)d_in[14];
    const float* b1     = (const float*)d_in[15];
    const float* w2     = (const float*)d_in[16];
    const float* b2     = (const float*)d_in[17];
    const float* w3     = (const float*)d_in[18];
    const float* b3     = (const float*)d_in[19];
    float* outp = (float*)d_out;

    float* part  = (float*)d_ws;                              // [2][16][1024] f32
    float* Kp    = (float*)((char*)d_ws + 393216);            // 3*3*32 f32
    short* U16   = (short*)((char*)d_ws + 394368);            // 3*1024*32 f16
    short* V16   = (short*)((char*)d_ws + 590976);            // 3*1024*32 f16
    short* w2f16 = (short*)((char*)d_ws + 787584);            // 9216 f16 swizzled

    dim3 g1(8, 16, 2);
    gnn_kernel<<<g1, 512, 0, stream>>>(lig_nf, lig_ef, rec_nf, rec_ef,
                                       Wn, We, bn, be, part);
    pguv_kernel<<<32, 512, 0, stream>>>(lig_nf, rec_nf, W_hopi, w1, U16, V16);
    w2pack_kernel<<<1, 512, 0, stream>>>(w2, w2f16);
    cveck_kernel<<<1, 512, 0, stream>>>(W_hopi, b_hopi, w1, b1, part, Kp);
    dim3 g3(64, 64);
    conv_kernel<<<g3, 512, 0, stream>>>(U16, V16, Kp, w2f16, b2, w3, b3, outp);
}

// Round 22
// 118.312 us; speedup vs baseline: 1.2701x; 1.2701x over previous
//
#include <hip/hip_runtime.h>

// All tensors float32. Math structure exploited:
//  - softmax over axis of size 1 == 1.0 -> attn all-ones, Wa/ba dead.
//  - weighted = row-sum of tanh(agg), broadcast over COLUMNS (N==D quirk).
//  - lig_p = nf@Wl.T + const  ->  x0[h,i,j] = PL[i,h] + PR[j,h] + c[h]
//  - conv1 is LINEAR in rank-structured x0: y1_pre = U[xc][y] + V[yc][x] + K'.
//  - ROUND-22: r21 instrumentation decoded -- merged pp's 44us = pguv (re-
//    fetching 8MB of nf on 32 CUs, in-flight-bytes-limited ~6GB/s/CU). Fix:
//    P = nf@W.T computed INSIDE gnn (y==0 blocks already stage those nf rows;
//    +32x64 W tile in LDS, +2 MFMA/wave/K-step, P->workspace f16). New pp2's
//    uv role reads 4KB L2-hot P instead of 256KB nf. 3 dispatches.

typedef _Float16 half8 __attribute__((ext_vector_type(8)));
typedef _Float16 half4 __attribute__((ext_vector_type(4)));
typedef float    f32x4 __attribute__((ext_vector_type(4)));

__device__ __forceinline__ short f2h_bits(float f){
    _Float16 h = (_Float16)f;          // RNE
    return __builtin_bit_cast(short, h);
}
__device__ __forceinline__ half8 pack2(const float4& x, const float4& y){
    half8 r;
    r[0] = (_Float16)x.x; r[1] = (_Float16)x.y;
    r[2] = (_Float16)x.z; r[3] = (_Float16)x.w;
    r[4] = (_Float16)y.x; r[5] = (_Float16)y.y;
    r[6] = (_Float16)y.z; r[7] = (_Float16)y.w;
    return r;
}
__device__ __forceinline__ half4 pack4(const float4& x){
    half4 r;
    r[0] = (_Float16)x.x; r[1] = (_Float16)x.y;
    r[2] = (_Float16)x.z; r[3] = (_Float16)x.w;
    return r;
}
__device__ __forceinline__ float tanh_fast(float x){
    float e = __expf(2.f * x);
    return 1.f - 2.f / (e + 1.f);
}

// ci-block swizzle (round-4 verified layout)
#define SWZ(c) ((((c) >> 1) & 3) << 3)

// ---------------------------------------------------------------------------
// K1 (MFMA): gnn + P side-path. BM=128/BN=64/BK=64, 512 thr, depth-2 reg
// prefetch. grid (8,16,2). y==0 blocks also accumulate P = nf@W.T from the
// already-staged As tiles (first 16 K-steps) against a 32x64 W tile (Bs2).
// ---------------------------------------------------------------------------
#define GNN_LOAD(AV, BV, KBN) {                                              \
    const int kbn_ = (KBN) & 2047;                                           \
    const float* Asrc_ = (kbn_ < 1024) ? A0 : A1;                            \
    const float* Bsrc_ = (kbn_ < 1024) ? Wn : We;                            \
    const int kk_ = kbn_ & 1023;                                             \
    const float* ap_ = Asrc_ + (size_t)(j0 + arow) * 1024 + kk_ + akc;       \
    const float* bp_ = Bsrc_ + (size_t)(d0 + brow) * 1024 + kk_ + bkc;       \
    AV[0] = *reinterpret_cast<const float4*>(ap_);                           \
    AV[1] = *reinterpret_cast<const float4*>(ap_ + 4);                       \
    AV[2] = *reinterpret_cast<const float4*>(ap_ + 8);                       \
    AV[3] = *reinterpret_cast<const float4*>(ap_ + 12);                      \
    BV[0] = *reinterpret_cast<const float4*>(bp_);                           \
    BV[1] = *reinterpret_cast<const float4*>(bp_ + 4);                       \
}

#define GNN_STAGE(AV, BV) {                                                  \
    const int ga_ = (t & 3) * 2;                                             \
    const int sa_ = arow & 7;                                                \
    *reinterpret_cast<half8*>(&As[arow * 64 + ((ga_    ) ^ sa_) * 8]) = pack2(AV[0], AV[1]); \
    *reinterpret_cast<half8*>(&As[arow * 64 + ((ga_ + 1) ^ sa_) * 8]) = pack2(AV[2], AV[3]); \
    *reinterpret_cast<half8*>(&Bs[brow * 64 + ((t & 7) ^ (brow & 7)) * 8]) = pack2(BV[0], BV[1]); \
}

// stage the 32x64 W_hopi K-slab into Bs2 (fresh load; y==0 blocks only)
#define GNN_STAGE_W(KBS) {                                                   \
    const int r32_ = t >> 4;                                                 \
    const int kc_  = (t & 15) * 4;                                           \
    float4 wv_ = *reinterpret_cast<const float4*>(                           \
        Wp + (size_t)r32_ * 2048 + (KBS) + kc_);                             \
    *reinterpret_cast<half4*>(                                               \
        &Bs2[r32_ * 64 + ((((t & 15) >> 1)) ^ (r32_ & 7)) * 8 + (t & 1) * 4]) = pack4(wv_); \
}

#define GNN_MFMA() {                                                         \
    _Pragma("unroll")                                                        \
    for (int ks = 0; ks < 2; ++ks){                                          \
        half8 Af[2], Bf[2];                                                  \
        _Pragma("unroll")                                                    \
        for (int m = 0; m < 2; ++m){                                         \
            int row = wm * 32 + m * 16 + lr;                                 \
            int g   = ((ks * 4 + lg) ^ (row & 7)) * 8;                       \
            Af[m] = *reinterpret_cast<const half8*>(&As[row * 64 + g]);      \
        }                                                                    \
        _Pragma("unroll")                                                    \
        for (int n = 0; n < 2; ++n){                                         \
            int col = wn * 32 + n * 16 + lr;                                 \
            int g   = ((ks * 4 + lg) ^ (col & 7)) * 8;                       \
            Bf[n] = *reinterpret_cast<const half8*>(&Bs[col * 64 + g]);      \
        }                                                                    \
        _Pragma("unroll")                                                    \
        for (int m = 0; m < 2; ++m)                                          \
            _Pragma("unroll")                                                \
            for (int n = 0; n < 2; ++n)                                      \
                acc[m][n] = __builtin_amdgcn_mfma_f32_16x16x32_f16(          \
                    Af[m], Bf[n], acc[m][n], 0, 0, 0);                       \
    }                                                                        \
}

// P side-path MFMA: wave wid owns M-rows wid*16..+15; cols = 32 h
#define GNN_PMFMA() {                                                        \
    _Pragma("unroll")                                                        \
    for (int ks = 0; ks < 2; ++ks){                                          \
        int prow = wid * 16 + lr;                                            \
        half8 Af = *reinterpret_cast<const half8*>(                          \
            &As[prow * 64 + ((ks * 4 + lg) ^ (prow & 7)) * 8]);              \
        _Pragma("unroll")                                                    \
        for (int n = 0; n < 2; ++n){                                         \
            int col = n * 16 + lr;                                           \
            half8 Bf2 = *reinterpret_cast<const half8*>(                     \
                &Bs2[col * 64 + ((ks * 4 + lg) ^ (col & 7)) * 8]);           \
            pacc[n] = __builtin_amdgcn_mfma_f32_16x16x32_f16(                \
                Af, Bf2, pacc[n], 0, 0, 0);                                  \
        }                                                                    \
    }                                                                        \
}

__global__ __launch_bounds__(512) void gnn_kernel(
    const float* __restrict__ lig_nf, const float* __restrict__ lig_ef,
    const float* __restrict__ rec_nf, const float* __restrict__ rec_ef,
    const float* __restrict__ Wn, const float* __restrict__ We,
    const float* __restrict__ bn, const float* __restrict__ be,
    const float* __restrict__ W_hopi,
    float* __restrict__ part,   // [2][16][1024]
    short* __restrict__ Pw)     // [2][1024][32] f16
{
    __shared__ __attribute__((aligned(16))) short As[128 * 64];
    __shared__ __attribute__((aligned(16))) short Bs[64 * 64];
    __shared__ __attribute__((aligned(16))) short Bs2[32 * 64];
    __shared__ float red[128][2];

    const int t  = threadIdx.x;
    const int cx = blockIdx.z;
    const float* A0 = cx ? rec_nf : lig_nf;
    const float* A1 = cx ? rec_ef : lig_ef;
    const float* Wp = W_hopi + (cx ? 1024 : 0);
    const int j0 = blockIdx.x * 128;
    const int d0 = blockIdx.y * 64;
    const bool doP = (blockIdx.y == 0);

    const int wid  = t >> 6;
    const int wm   = wid >> 1;
    const int wn   = wid & 1;
    const int lane = t & 63;
    const int lr   = lane & 15;
    const int lg   = lane >> 4;

    f32x4 acc[2][2];
    #pragma unroll
    for (int m = 0; m < 2; ++m)
        #pragma unroll
        for (int n = 0; n < 2; ++n)
            acc[m][n] = (f32x4){0.f, 0.f, 0.f, 0.f};
    f32x4 pacc[2];
    pacc[0] = (f32x4){0.f, 0.f, 0.f, 0.f};
    pacc[1] = (f32x4){0.f, 0.f, 0.f, 0.f};

    const int arow = t >> 2;
    const int akc  = (t & 3) * 16;
    const int brow = t >> 3;
    const int bkc  = (t & 7) * 8;

    float4 avA[4], bvA[2], avB[4], bvB[2];
    GNN_LOAD(avA, bvA, 0);
    GNN_LOAD(avB, bvB, 64);

    for (int kb = 0; kb < 2048; kb += 128){
        const bool pA = doP && (kb < 1024);
        const bool pB = doP && (kb + 64 < 1024);
        __syncthreads();
        GNN_STAGE(avA, bvA);
        if (pA) GNN_STAGE_W(kb);
        GNN_LOAD(avA, bvA, kb + 128);
        __syncthreads();
        GNN_MFMA();
        if (pA) GNN_PMFMA();
        __syncthreads();
        GNN_STAGE(avB, bvB);
        if (pB) GNN_STAGE_W(kb + 64);
        GNN_LOAD(avB, bvB, kb + 192);
        __syncthreads();
        GNN_MFMA();
        if (pB) GNN_PMFMA();
    }

    float rowsum[2][4];
    #pragma unroll
    for (int m = 0; m < 2; ++m)
        #pragma unroll
        for (int jj = 0; jj < 4; ++jj) rowsum[m][jj] = 0.f;
    #pragma unroll
    for (int n = 0; n < 2; ++n){
        int d = d0 + wn * 32 + n * 16 + lr;
        float bias = bn[d] + be[d];
        #pragma unroll
        for (int m = 0; m < 2; ++m)
            #pragma unroll
            for (int jj = 0; jj < 4; ++jj)
                rowsum[m][jj] += tanh_fast(acc[m][n][jj] + bias);
    }
    #pragma unroll
    for (int mask = 1; mask < 16; mask <<= 1)
        #pragma unroll
        for (int m = 0; m < 2; ++m)
            #pragma unroll
            for (int jj = 0; jj < 4; ++jj)
                rowsum[m][jj] += __shfl_xor(rowsum[m][jj], mask);
    __syncthreads();
    if (lr == 0){
        #pragma unroll
        for (int m = 0; m < 2; ++m)
            #pragma unroll
            for (int jj = 0; jj < 4; ++jj)
                red[wm * 32 + m * 16 + lg * 4 + jj][wn] = rowsum[m][jj];
    }
    __syncthreads();
    if (t < 128)
        part[(size_t)cx * 16384 + (size_t)blockIdx.y * 1024 + j0 + t]
            = red[t][0] + red[t][1];

    // P epilogue: y==0 blocks write their 128 rows of P (f16)
    if (doP){
        #pragma unroll
        for (int n = 0; n < 2; ++n)
            #pragma unroll
            for (int jj = 0; jj < 4; ++jj){
                int grow = j0 + wid * 16 + lg * 4 + jj;
                Pw[(size_t)cx * 32768 + (size_t)grow * 32 + n * 16 + lr]
                    = f2h_bits(pacc[n][jj]);
            }
    }
}

// ---------------------------------------------------------------------------
// K2: pp2_kernel. grid 34 x 512 thr.
//  roles 0..31: uv -- stage P rows r0-1..r0+64 from Pw (L2-hot, 4KB) into
//               Pz, Ws from contiguous tap loads, one barrier, uv MFMA.
//  role 32: cveck -> Kp ; role 33: w2pack -> w2f16
// ---------------------------------------------------------------------------
__global__ __launch_bounds__(512) void pp2_kernel(
    const float* __restrict__ W_hopi, const float* __restrict__ b_hopi,
    const float* __restrict__ w1, const float* __restrict__ b1,
    const float* __restrict__ w2,
    const float* __restrict__ part, const short* __restrict__ Pw,
    float* __restrict__ Kp, short* __restrict__ U16, short* __restrict__ V16,
    short* __restrict__ w2f16)
{
    __shared__ __attribute__((aligned(16))) char smem[47232];
    const int t = threadIdx.x;
    const int role = blockIdx.x;

    if (role < 32){
        short* Pz = reinterpret_cast<short*>(smem);            // 66 x stride40
        short* Ws = reinterpret_cast<short*>(smem + 5376);     // 3x32 x stride104

        const int cx = role >> 4;
        const int r0 = (role & 15) * 64;
        short* O = cx ? V16 : U16;
        const short* Psrc = Pw + (size_t)cx * 32768;

        const int wid = t >> 6;
        const int lane = t & 63;
        const int lr = lane & 15;
        const int lg = lane >> 4;

        // ---- stage Pz rows 0..65 = global r0-1 .. r0+64 (zero OOB) ----
        for (int idx = t; idx < 2112; idx += 512){
            int l = idx >> 5;
            int h = idx & 31;
            int gr = r0 - 1 + l;
            short v = 0;
            if ((unsigned)gr < 1024u) v = Psrc[(size_t)gr * 32 + h];
            Pz[l * 40 + h] = v;
        }

        // ---- Ws from contiguous tap loads ----
        #pragma unroll
        for (int q = 0; q < 2; ++q){
            int pr = t * 2 + q;              // (co,ci) pair 0..1023
            int co = pr >> 5;
            int ci = pr & 31;
            const float* wp = w1 + co * 288 + ci * 9;
            float tap[9];
            #pragma unroll
            for (int e = 0; e < 9; ++e) tap[e] = wp[e];
            #pragma unroll
            for (int d = 0; d < 3; ++d){
                float ta, tb, tc;
                if (cx == 0){ ta = tap[d * 3 + 0]; tb = tap[d * 3 + 1]; tc = tap[d * 3 + 2]; }
                else        { ta = tap[0 + d];     tb = tap[3 + d];     tc = tap[6 + d]; }
                Ws[(0 * 32 + co) * 104 + d * 32 + ci] = f2h_bits(ta + tb + tc);
                Ws[(1 * 32 + co) * 104 + d * 32 + ci] = f2h_bits(tb + tc);
                Ws[(2 * 32 + co) * 104 + d * 32 + ci] = f2h_bits(ta + tb);
            }
        }
        __syncthreads();

        // ---- uv GEMM (waves 0-3): 64 rows x 32 co x K=96 ----
        if (wid < 4){
            f32x4 uacc[3][2];
            #pragma unroll
            for (int cs = 0; cs < 3; ++cs)
                #pragma unroll
                for (int n = 0; n < 2; ++n)
                    uacc[cs][n] = (f32x4){0.f, 0.f, 0.f, 0.f};
            #pragma unroll
            for (int d = 0; d < 3; ++d){
                int ar = wid * 16 + lr;
                half8 Ap = *reinterpret_cast<const half8*>(
                    &Pz[(ar + d) * 40 + lg * 8]);
                #pragma unroll
                for (int cs = 0; cs < 3; ++cs)
                    #pragma unroll
                    for (int n = 0; n < 2; ++n){
                        half8 Bp = *reinterpret_cast<const half8*>(
                            &Ws[(cs * 32 + n * 16 + lr) * 104 + d * 32 + lg * 8]);
                        uacc[cs][n] = __builtin_amdgcn_mfma_f32_16x16x32_f16(
                            Ap, Bp, uacc[cs][n], 0, 0, 0);
                    }
            }
            #pragma unroll
            for (int cs = 0; cs < 3; ++cs)
                #pragma unroll
                for (int n = 0; n < 2; ++n)
                    #pragma unroll
                    for (int jj = 0; jj < 4; ++jj){
                        int grow = r0 + wid * 16 + lg * 4 + jj;
                        O[((size_t)(cs << 10) + grow) * 32 + n * 16 + lr]
                            = f2h_bits(uacc[cs][n][jj]);
                    }
        }
        return;
    }

    if (role == 33){
        #pragma unroll
        for (int q = 0; q < 18; ++q){
            int e = t + q * 512;
            int co  = e / 288;
            int rem = e - co * 288;
            int ci  = rem / 9;
            int tap = rem - ci * 9;
            w2f16[(tap * 32 + co) * 32 + (ci ^ SWZ(co))] = f2h_bits(w2[e]);
        }
        return;
    }

    // ---------------- cveck role ----------------
    float* ws_l = reinterpret_cast<float*>(smem);
    float* ws_r = reinterpret_cast<float*>(smem + 4096);
    float* red  = reinterpret_cast<float*>(smem + 8192);
    float* cvs  = reinterpret_cast<float*>(smem + 10240);
    float* w1s  = reinterpret_cast<float*>(smem + 10368);

    #pragma unroll
    for (int q = 0; q < 5; ++q){
        int i4 = t + q * 512;
        if (i4 < 2304)
            *reinterpret_cast<float4*>(&w1s[i4 * 4]) =
                *reinterpret_cast<const float4*>(w1 + i4 * 4);
    }
    for (int j = t; j < 1024; j += 512){
        float sl = 0.f, sr = 0.f;
        #pragma unroll
        for (int b = 0; b < 16; ++b){
            sl += part[b * 1024 + j];
            sr += part[16384 + b * 1024 + j];
        }
        ws_l[j] = sl; ws_r[j] = sr;
    }
    __syncthreads();
    {
        const int h = t & 31;
        const int seg = t >> 5;
        const float* wl = W_hopi + (size_t)h * 2048 + seg * 64;
        const float* wr = wl + 1024;
        float s = 0.f;
        #pragma unroll 8
        for (int j = 0; j < 64; j += 4){
            float4 a = *reinterpret_cast<const float4*>(wl + j);
            float4 b = *reinterpret_cast<const float4*>(wr + j);
            const float* l = &ws_l[seg * 64 + j];
            const float* r = &ws_r[seg * 64 + j];
            s = fmaf(l[0], a.x, s); s = fmaf(l[1], a.y, s);
            s = fmaf(l[2], a.z, s); s = fmaf(l[3], a.w, s);
            s = fmaf(r[0], b.x, s); s = fmaf(r[1], b.y, s);
            s = fmaf(r[2], b.z, s); s = fmaf(r[3], b.w, s);
        }
        red[t] = s;
    }
    __syncthreads();
    if (t < 32){
        float tot = b_hopi[t];
        #pragma unroll
        for (int g = 0; g < 16; ++g) tot += red[g * 32 + t];
        cvs[t] = tot;
    }
    __syncthreads();
    for (int e = t; e < 288; e += 512){
        int co  = e & 31;
        int cse = e >> 5;
        int yc  = cse / 3, xc = cse - yc * 3;
        float sum = b1[co];
        for (int ci = 0; ci < 32; ++ci){
            const float* wp = &w1s[co * 288 + ci * 9];
            float t00 = wp[0], t01 = wp[1], t02 = wp[2];
            float t10 = wp[3], t11 = wp[4], t12 = wp[5];
            float t20 = wp[6], t21 = wp[7], t22 = wp[8];
            float r0, r1, r2;
            if (xc == 0){ r0 = t00+t01+t02; r1 = t10+t11+t12; r2 = t20+t21+t22; }
            else if (xc == 1){ r0 = t01+t02; r1 = t11+t12; r2 = t21+t22; }
            else { r0 = t00+t01; r1 = t10+t11; r2 = t20+t21; }
            float wsum = (yc == 0) ? (r0+r1+r2) : ((yc == 1) ? (r1+r2) : (r0+r1));
            sum = fmaf(cvs[ci], wsum, sum);
        }
        Kp[cse * 32 + co] = sum;
    }
}

// ---------------------------------------------------------------------------
// K3: stage ys = relu(U+V+K') (interior fast path in packed f16), wB by uint4
// copy of prepacked w2f16, then conv2+relu+conv3 on f16 MFMA. LDS = 39,168 B.
// block 512, grid 64x64. (round-16 verbatim)
// ---------------------------------------------------------------------------
__global__ __launch_bounds__(512) void conv_kernel(
    const short* __restrict__ U16, const short* __restrict__ V16,
    const float* __restrict__ Kp, const short* __restrict__ w2f16,
    const float* __restrict__ b2,
    const float* __restrict__ w3, const float* __restrict__ b3,
    float* __restrict__ outp)
{
    __shared__ __attribute__((aligned(16))) short ys[18 * 18 * 32];
    __shared__ __attribute__((aligned(16))) short wB[9 * 32 * 32];

    const int t    = threadIdx.x;
    const int oy0  = blockIdx.y * 16;
    const int ox0  = blockIdx.x * 16;
    const int wid  = t >> 6;
    const int lane = t & 63;
    const int lr   = lane & 15;
    const int lg   = lane >> 4;

    {
        const uint4* src = reinterpret_cast<const uint4*>(w2f16);
        uint4* dst = reinterpret_cast<uint4*>(wB);
        #pragma unroll
        for (int e = t; e < 1152; e += 512)
            dst[e] = src[e];
    }
    const bool interior = (blockIdx.x >= 1) & (blockIdx.x <= 62) &
                          (blockIdx.y >= 1) & (blockIdx.y <= 62);
    if (interior){
        const int cp = (t & 7) * 4;
        half4 k00;
        {
            float4 kf = *reinterpret_cast<const float4*>(&Kp[cp]);
            k00[0] = (_Float16)kf.x; k00[1] = (_Float16)kf.y;
            k00[2] = (_Float16)kf.z; k00[3] = (_Float16)kf.w;
        }
        #pragma unroll
        for (int pass = 0; pass < 6; ++pass){
            int idx = t + pass * 512;
            if (idx < 2592){
                int po  = idx >> 3;
                int ryo = po / 18;
                int rxo = po - ryo * 18;
                int gy = oy0 - 1 + ryo, gx = ox0 - 1 + rxo;
                half4 u = *reinterpret_cast<const half4*>(&U16[gy * 32 + cp]);
                half4 v = *reinterpret_cast<const half4*>(&V16[gx * 32 + cp]);
                half4 r = u + v + k00;
                #pragma unroll
                for (int e = 0; e < 4; ++e)
                    r[e] = r[e] > (_Float16)0.f ? r[e] : (_Float16)0.f;
                *reinterpret_cast<half4*>(&ys[po * 32 + (cp ^ SWZ(rxo))]) = r;
            }
        }
    } else {
        #pragma unroll
        for (int pass = 0; pass < 6; ++pass){
            int idx = t + pass * 512;
            if (idx < 2592){
                int po  = idx >> 3;
                int cp  = (idx & 7) * 4;
                int ryo = po / 18;
                int rxo = po - ryo * 18;
                int gy = oy0 - 1 + ryo, gx = ox0 - 1 + rxo;
                half4 h = {(_Float16)0.f, (_Float16)0.f, (_Float16)0.f, (_Float16)0.f};
                if ((unsigned)gy < 1024u && (unsigned)gx < 1024u){
                    int yc = (gy == 0) ? 1 : ((gy == 1023) ? 2 : 0);
                    int xc = (gx == 0) ? 1 : ((gx == 1023) ? 2 : 0);
                    half4 u = *reinterpret_cast<const half4*>(
                        &U16[((size_t)(xc << 10) + gy) * 32 + cp]);
                    half4 v = *reinterpret_cast<const half4*>(
                        &V16[((size_t)(yc << 10) + gx) * 32 + cp]);
                    float4 k = *reinterpret_cast<const float4*>(&Kp[(yc * 3 + xc) * 32 + cp]);
                    h[0] = (_Float16)fmaxf((float)u[0] + (float)v[0] + k.x, 0.f);
                    h[1] = (_Float16)fmaxf((float)u[1] + (float)v[1] + k.y, 0.f);
                    h[2] = (_Float16)fmaxf((float)u[2] + (float)v[2] + k.z, 0.f);
                    h[3] = (_Float16)fmaxf((float)u[3] + (float)v[3] + k.w, 0.f);
                }
                *reinterpret_cast<half4*>(&ys[po * 32 + (cp ^ SWZ(rxo))]) = h;
            }
        }
    }
    __syncthreads();

    {
        half8 Bf[2][9];
        float bias[2], w3v[2];
        #pragma unroll
        for (int n = 0; n < 2; ++n){
            int co = n * 16 + lr;
            bias[n] = b2[co];
            w3v[n]  = w3[co];
            #pragma unroll
            for (int tap = 0; tap < 9; ++tap)
                Bf[n][tap] = *reinterpret_cast<const half8*>(
                    &wB[(tap * 32 + co) * 32 + ((lg * 8) ^ SWZ(co))]);
        }
        const float b3v = b3[0];
        for (int s = wid; s < 16; s += 8){
            int p  = s * 16 + lr;
            int ry = p >> 4;
            int rx = p & 15;
            f32x4 acc0 = {0.f, 0.f, 0.f, 0.f};
            f32x4 acc1 = {0.f, 0.f, 0.f, 0.f};
            #pragma unroll
            for (int tap = 0; tap < 9; ++tap){
                const int dy = tap / 3, dx = tap - (tap / 3) * 3;
                int pix = (ry + dy) * 18 + rx + dx;
                half8 A = *reinterpret_cast<const half8*>(
                    &ys[pix * 32 + ((lg * 8) ^ SWZ(rx + dx))]);
                acc0 = __builtin_amdgcn_mfma_f32_16x16x32_f16(A, Bf[0][tap], acc0, 0, 0, 0);
                acc1 = __builtin_amdgcn_mfma_f32_16x16x32_f16(A, Bf[1][tap], acc1, 0, 0, 0);
            }
            float part[4];
            #pragma unroll
            for (int j = 0; j < 4; ++j)
                part[j] = w3v[0] * fmaxf(acc0[j] + bias[0], 0.f)
                        + w3v[1] * fmaxf(acc1[j] + bias[1], 0.f);
            #pragma unroll
            for (int m = 1; m < 16; m <<= 1)
                #pragma unroll
                for (int j = 0; j < 4; ++j)
                    part[j] += __shfl_xor(part[j], m);
            if (lr == 0){
                float4 o = make_float4(part[0] + b3v, part[1] + b3v,
                                       part[2] + b3v, part[3] + b3v);
                *reinterpret_cast<float4*>(outp + (size_t)(oy0 + s) * 1024 + ox0 + lg * 4) = o;
            }
        }
    }
}

// ---------------------------------------------------------------------------
extern "C" void kernel_launch(void* const* d_in, const int* in_sizes, int n_in,
                              void* d_out, int out_size, void* d_ws, size_t ws_size,
                              hipStream_t stream)
{
    const float* lig_nf = (const float*)d_in[0];
    const float* lig_ef = (const float*)d_in[1];
    const float* rec_nf = (const float*)d_in[3];
    const float* rec_ef = (const float*)d_in[4];
    const float* Wn     = (const float*)d_in[6];
    const float* bn     = (const float*)d_in[7];
    const float* We     = (const float*)d_in[8];
    const float* be     = (const float*)d_in[9];
    const float* W_hopi = (const float*)d_in[12];
    const float* b_hopi = (const float*)d_in[13];
    const float* w1     = (const float*)d_in[14];
    const float* b1     = (const float*)d_in[15];
    const float* w2     = (const float*)d_in[16];
    const float* b2     = (const float*)d_in[17];
    const float* w3     = (const float*)d_in[18];
    const float* b3     = (const float*)d_in[19];
    float* outp = (float*)d_out;

    float* part  = (float*)d_ws;                              // [2][16][1024] f32
    short* Pw    = (short*)((char*)d_ws + 131072);            // [2][1024][32] f16
    float* Kp    = (float*)((char*)d_ws + 393216);            // 3*3*32 f32
    short* U16   = (short*)((char*)d_ws + 394368);            // 3*1024*32 f16
    short* V16   = (short*)((char*)d_ws + 590976);            // 3*1024*32 f16
    short* w2f16 = (short*)((char*)d_ws + 787584);            // 9216 f16 swizzled

    dim3 g1(8, 16, 2);
    gnn_kernel<<<g1, 512, 0, stream>>>(lig_nf, lig_ef, rec_nf, rec_ef,
                                       Wn, We, bn, be, W_hopi, part, Pw);
    pp2_kernel<<<34, 512, 0, stream>>>(W_hopi, b_hopi, w1, b1, w2,
                                       part, Pw, Kp, U16, V16, w2f16);
    dim3 g3(64, 64);
    conv_kernel<<<g3, 512, 0, stream>>>(U16, V16, Kp, w2f16, b2, w3, b3, outp);
}

// Round 23
// 111.477 us; speedup vs baseline: 1.3480x; 1.0613x over previous
//
#include <hip/hip_runtime.h>

// All tensors float32. Math structure exploited:
//  - softmax over axis of size 1 == 1.0 -> attn all-ones, Wa/ba dead.
//  - weighted = row-sum of tanh(agg), broadcast over COLUMNS (N==D quirk).
//  - lig_p = nf@Wl.T + const  ->  x0[h,i,j] = PL[i,h] + PR[j,h] + c[h]
//  - conv1 is LINEAR in rank-structured x0: y1_pre = U[xc][y] + V[yc][x] + K'.
//  - ROUND-23 ledger (reconciled r18/r21/r22): gnn 20, pguv 42, cveck 30,
//    conv 46. Fixes: (1) cveck's 256KB W_hopi dot parallelized across 16
//    partial_c blocks in pp2 + tiny kfin finisher (1-block kernels are
//    in-flight-bytes-limited ~6GB/s/CU); (2) gnn's P side-path split into
//    branch-free loop variants (if(pA) inside the hot loop pessimized all
//    blocks). conv = round-16 verbatim.

typedef _Float16 half8 __attribute__((ext_vector_type(8)));
typedef _Float16 half4 __attribute__((ext_vector_type(4)));
typedef float    f32x4 __attribute__((ext_vector_type(4)));

__device__ __forceinline__ short f2h_bits(float f){
    _Float16 h = (_Float16)f;          // RNE
    return __builtin_bit_cast(short, h);
}
__device__ __forceinline__ half8 pack2(const float4& x, const float4& y){
    half8 r;
    r[0] = (_Float16)x.x; r[1] = (_Float16)x.y;
    r[2] = (_Float16)x.z; r[3] = (_Float16)x.w;
    r[4] = (_Float16)y.x; r[5] = (_Float16)y.y;
    r[6] = (_Float16)y.z; r[7] = (_Float16)y.w;
    return r;
}
__device__ __forceinline__ half4 pack4(const float4& x){
    half4 r;
    r[0] = (_Float16)x.x; r[1] = (_Float16)x.y;
    r[2] = (_Float16)x.z; r[3] = (_Float16)x.w;
    return r;
}
__device__ __forceinline__ float tanh_fast(float x){
    float e = __expf(2.f * x);
    return 1.f - 2.f / (e + 1.f);
}

// ci-block swizzle (round-4 verified layout)
#define SWZ(c) ((((c) >> 1) & 3) << 3)

// ---------------------------------------------------------------------------
// K1 (MFMA): gnn + P side-path, branch-free loop variants.
// BM=128/BN=64/BK=64, 512 thr, depth-2 reg prefetch. grid (8,16,2).
// ---------------------------------------------------------------------------
#define GNN_LOAD(AV, BV, KBN) {                                              \
    const int kbn_ = (KBN) & 2047;                                           \
    const float* Asrc_ = (kbn_ < 1024) ? A0 : A1;                            \
    const float* Bsrc_ = (kbn_ < 1024) ? Wn : We;                            \
    const int kk_ = kbn_ & 1023;                                             \
    const float* ap_ = Asrc_ + (size_t)(j0 + arow) * 1024 + kk_ + akc;       \
    const float* bp_ = Bsrc_ + (size_t)(d0 + brow) * 1024 + kk_ + bkc;       \
    AV[0] = *reinterpret_cast<const float4*>(ap_);                           \
    AV[1] = *reinterpret_cast<const float4*>(ap_ + 4);                       \
    AV[2] = *reinterpret_cast<const float4*>(ap_ + 8);                       \
    AV[3] = *reinterpret_cast<const float4*>(ap_ + 12);                      \
    BV[0] = *reinterpret_cast<const float4*>(bp_);                           \
    BV[1] = *reinterpret_cast<const float4*>(bp_ + 4);                       \
}

#define GNN_STAGE(AV, BV) {                                                  \
    const int ga_ = (t & 3) * 2;                                             \
    const int sa_ = arow & 7;                                                \
    *reinterpret_cast<half8*>(&As[arow * 64 + ((ga_    ) ^ sa_) * 8]) = pack2(AV[0], AV[1]); \
    *reinterpret_cast<half8*>(&As[arow * 64 + ((ga_ + 1) ^ sa_) * 8]) = pack2(AV[2], AV[3]); \
    *reinterpret_cast<half8*>(&Bs[brow * 64 + ((t & 7) ^ (brow & 7)) * 8]) = pack2(BV[0], BV[1]); \
}

#define GNN_STAGE_W(KBS) {                                                   \
    const int r32_ = t >> 4;                                                 \
    const int kc_  = (t & 15) * 4;                                           \
    float4 wv_ = *reinterpret_cast<const float4*>(                           \
        Wp + (size_t)r32_ * 2048 + (KBS) + kc_);                             \
    *reinterpret_cast<half4*>(                                               \
        &Bs2[r32_ * 64 + ((((t & 15) >> 1)) ^ (r32_ & 7)) * 8 + (t & 1) * 4]) = pack4(wv_); \
}

#define GNN_MFMA() {                                                         \
    _Pragma("unroll")                                                        \
    for (int ks = 0; ks < 2; ++ks){                                          \
        half8 Af[2], Bf[2];                                                  \
        _Pragma("unroll")                                                    \
        for (int m = 0; m < 2; ++m){                                         \
            int row = wm * 32 + m * 16 + lr;                                 \
            int g   = ((ks * 4 + lg) ^ (row & 7)) * 8;                       \
            Af[m] = *reinterpret_cast<const half8*>(&As[row * 64 + g]);      \
        }                                                                    \
        _Pragma("unroll")                                                    \
        for (int n = 0; n < 2; ++n){                                         \
            int col = wn * 32 + n * 16 + lr;                                 \
            int g   = ((ks * 4 + lg) ^ (col & 7)) * 8;                       \
            Bf[n] = *reinterpret_cast<const half8*>(&Bs[col * 64 + g]);      \
        }                                                                    \
        _Pragma("unroll")                                                    \
        for (int m = 0; m < 2; ++m)                                          \
            _Pragma("unroll")                                                \
            for (int n = 0; n < 2; ++n)                                      \
                acc[m][n] = __builtin_amdgcn_mfma_f32_16x16x32_f16(          \
                    Af[m], Bf[n], acc[m][n], 0, 0, 0);                       \
    }                                                                        \
}

#define GNN_PMFMA() {                                                        \
    _Pragma("unroll")                                                        \
    for (int ks = 0; ks < 2; ++ks){                                          \
        int prow = wid * 16 + lr;                                            \
        half8 Af = *reinterpret_cast<const half8*>(                          \
            &As[prow * 64 + ((ks * 4 + lg) ^ (prow & 7)) * 8]);              \
        _Pragma("unroll")                                                    \
        for (int n = 0; n < 2; ++n){                                         \
            int col = n * 16 + lr;                                           \
            half8 Bf2 = *reinterpret_cast<const half8*>(                     \
                &Bs2[col * 64 + ((ks * 4 + lg) ^ (col & 7)) * 8]);           \
            pacc[n] = __builtin_amdgcn_mfma_f32_16x16x32_f16(                \
                Af, Bf2, pacc[n], 0, 0, 0);                                  \
        }                                                                    \
    }                                                                        \
}

__global__ __launch_bounds__(512) void gnn_kernel(
    const float* __restrict__ lig_nf, const float* __restrict__ lig_ef,
    const float* __restrict__ rec_nf, const float* __restrict__ rec_ef,
    const float* __restrict__ Wn, const float* __restrict__ We,
    const float* __restrict__ bn, const float* __restrict__ be,
    const float* __restrict__ W_hopi,
    float* __restrict__ part,   // [2][16][1024]
    short* __restrict__ Pw)     // [2][1024][32] f16
{
    __shared__ __attribute__((aligned(16))) short As[128 * 64];
    __shared__ __attribute__((aligned(16))) short Bs[64 * 64];
    __shared__ __attribute__((aligned(16))) short Bs2[32 * 64];
    __shared__ float red[128][2];

    const int t  = threadIdx.x;
    const int cx = blockIdx.z;
    const float* A0 = cx ? rec_nf : lig_nf;
    const float* A1 = cx ? rec_ef : lig_ef;
    const float* Wp = W_hopi + (cx ? 1024 : 0);
    const int j0 = blockIdx.x * 128;
    const int d0 = blockIdx.y * 64;
    const bool doP = (blockIdx.y == 0);

    const int wid  = t >> 6;
    const int wm   = wid >> 1;
    const int wn   = wid & 1;
    const int lane = t & 63;
    const int lr   = lane & 15;
    const int lg   = lane >> 4;

    f32x4 acc[2][2];
    #pragma unroll
    for (int m = 0; m < 2; ++m)
        #pragma unroll
        for (int n = 0; n < 2; ++n)
            acc[m][n] = (f32x4){0.f, 0.f, 0.f, 0.f};
    f32x4 pacc[2];
    pacc[0] = (f32x4){0.f, 0.f, 0.f, 0.f};
    pacc[1] = (f32x4){0.f, 0.f, 0.f, 0.f};

    const int arow = t >> 2;
    const int akc  = (t & 3) * 16;
    const int brow = t >> 3;
    const int bkc  = (t & 7) * 8;

    float4 avA[4], bvA[2], avB[4], bvB[2];
    GNN_LOAD(avA, bvA, 0);
    GNN_LOAD(avB, bvB, 64);

    if (doP){
        // first half: with P side-path (branch-free inside)
        for (int kb = 0; kb < 1024; kb += 128){
            __syncthreads();
            GNN_STAGE(avA, bvA);
            GNN_STAGE_W(kb);
            GNN_LOAD(avA, bvA, kb + 128);
            __syncthreads();
            GNN_MFMA();
            GNN_PMFMA();
            __syncthreads();
            GNN_STAGE(avB, bvB);
            GNN_STAGE_W(kb + 64);
            GNN_LOAD(avB, bvB, kb + 192);
            __syncthreads();
            GNN_MFMA();
            GNN_PMFMA();
        }
        // second half: clean
        for (int kb = 1024; kb < 2048; kb += 128){
            __syncthreads();
            GNN_STAGE(avA, bvA);
            GNN_LOAD(avA, bvA, kb + 128);
            __syncthreads();
            GNN_MFMA();
            __syncthreads();
            GNN_STAGE(avB, bvB);
            GNN_LOAD(avB, bvB, kb + 192);
            __syncthreads();
            GNN_MFMA();
        }
    } else {
        for (int kb = 0; kb < 2048; kb += 128){
            __syncthreads();
            GNN_STAGE(avA, bvA);
            GNN_LOAD(avA, bvA, kb + 128);
            __syncthreads();
            GNN_MFMA();
            __syncthreads();
            GNN_STAGE(avB, bvB);
            GNN_LOAD(avB, bvB, kb + 192);
            __syncthreads();
            GNN_MFMA();
        }
    }

    float rowsum[2][4];
    #pragma unroll
    for (int m = 0; m < 2; ++m)
        #pragma unroll
        for (int jj = 0; jj < 4; ++jj) rowsum[m][jj] = 0.f;
    #pragma unroll
    for (int n = 0; n < 2; ++n){
        int d = d0 + wn * 32 + n * 16 + lr;
        float bias = bn[d] + be[d];
        #pragma unroll
        for (int m = 0; m < 2; ++m)
            #pragma unroll
            for (int jj = 0; jj < 4; ++jj)
                rowsum[m][jj] += tanh_fast(acc[m][n][jj] + bias);
    }
    #pragma unroll
    for (int mask = 1; mask < 16; mask <<= 1)
        #pragma unroll
        for (int m = 0; m < 2; ++m)
            #pragma unroll
            for (int jj = 0; jj < 4; ++jj)
                rowsum[m][jj] += __shfl_xor(rowsum[m][jj], mask);
    __syncthreads();
    if (lr == 0){
        #pragma unroll
        for (int m = 0; m < 2; ++m)
            #pragma unroll
            for (int jj = 0; jj < 4; ++jj)
                red[wm * 32 + m * 16 + lg * 4 + jj][wn] = rowsum[m][jj];
    }
    __syncthreads();
    if (t < 128)
        part[(size_t)cx * 16384 + (size_t)blockIdx.y * 1024 + j0 + t]
            = red[t][0] + red[t][1];

    if (doP){
        #pragma unroll
        for (int n = 0; n < 2; ++n)
            #pragma unroll
            for (int jj = 0; jj < 4; ++jj){
                int grow = j0 + wid * 16 + lg * 4 + jj;
                Pw[(size_t)cx * 32768 + (size_t)grow * 32 + n * 16 + lr]
                    = f2h_bits(pacc[n][jj]);
            }
    }
}

// ---------------------------------------------------------------------------
// K2: pp2_kernel. grid 49 x 512 thr.
//  roles 0..31 : uv (reads L2-hot Pw, writes U16/V16)
//  roles 32..47: partial_c -- chunk q = role-32 covers 64 j's; computes
//                cpart[q][h] = sum_j wl[j] Wl[h,j] + wr[j] Wr[h,j]
//  role 48     : w2pack -> w2f16
// ---------------------------------------------------------------------------
__global__ __launch_bounds__(512) void pp2_kernel(
    const float* __restrict__ W_hopi,
    const float* __restrict__ w1, const float* __restrict__ w2,
    const float* __restrict__ part, const short* __restrict__ Pw,
    float* __restrict__ cpart,   // [16][32]
    short* __restrict__ U16, short* __restrict__ V16,
    short* __restrict__ w2f16)
{
    __shared__ __attribute__((aligned(16))) char smem[47232];
    const int t = threadIdx.x;
    const int role = blockIdx.x;

    if (role < 32){
        short* Pz = reinterpret_cast<short*>(smem);            // 66 x stride40
        short* Ws = reinterpret_cast<short*>(smem + 5376);     // 3x32 x stride104

        const int cx = role >> 4;
        const int r0 = (role & 15) * 64;
        short* O = cx ? V16 : U16;
        const short* Psrc = Pw + (size_t)cx * 32768;

        const int wid = t >> 6;
        const int lane = t & 63;
        const int lr = lane & 15;
        const int lg = lane >> 4;

        for (int idx = t; idx < 2112; idx += 512){
            int l = idx >> 5;
            int h = idx & 31;
            int gr = r0 - 1 + l;
            short v = 0;
            if ((unsigned)gr < 1024u) v = Psrc[(size_t)gr * 32 + h];
            Pz[l * 40 + h] = v;
        }

        #pragma unroll
        for (int q = 0; q < 2; ++q){
            int pr = t * 2 + q;
            int co = pr >> 5;
            int ci = pr & 31;
            const float* wp = w1 + co * 288 + ci * 9;
            float tap[9];
            #pragma unroll
            for (int e = 0; e < 9; ++e) tap[e] = wp[e];
            #pragma unroll
            for (int d = 0; d < 3; ++d){
                float ta, tb, tc;
                if (cx == 0){ ta = tap[d * 3 + 0]; tb = tap[d * 3 + 1]; tc = tap[d * 3 + 2]; }
                else        { ta = tap[0 + d];     tb = tap[3 + d];     tc = tap[6 + d]; }
                Ws[(0 * 32 + co) * 104 + d * 32 + ci] = f2h_bits(ta + tb + tc);
                Ws[(1 * 32 + co) * 104 + d * 32 + ci] = f2h_bits(tb + tc);
                Ws[(2 * 32 + co) * 104 + d * 32 + ci] = f2h_bits(ta + tb);
            }
        }
        __syncthreads();

        if (wid < 4){
            f32x4 uacc[3][2];
            #pragma unroll
            for (int cs = 0; cs < 3; ++cs)
                #pragma unroll
                for (int n = 0; n < 2; ++n)
                    uacc[cs][n] = (f32x4){0.f, 0.f, 0.f, 0.f};
            #pragma unroll
            for (int d = 0; d < 3; ++d){
                int ar = wid * 16 + lr;
                half8 Ap = *reinterpret_cast<const half8*>(
                    &Pz[(ar + d) * 40 + lg * 8]);
                #pragma unroll
                for (int cs = 0; cs < 3; ++cs)
                    #pragma unroll
                    for (int n = 0; n < 2; ++n){
                        half8 Bp = *reinterpret_cast<const half8*>(
                            &Ws[(cs * 32 + n * 16 + lr) * 104 + d * 32 + lg * 8]);
                        uacc[cs][n] = __builtin_amdgcn_mfma_f32_16x16x32_f16(
                            Ap, Bp, uacc[cs][n], 0, 0, 0);
                    }
            }
            #pragma unroll
            for (int cs = 0; cs < 3; ++cs)
                #pragma unroll
                for (int n = 0; n < 2; ++n)
                    #pragma unroll
                    for (int jj = 0; jj < 4; ++jj){
                        int grow = r0 + wid * 16 + lg * 4 + jj;
                        O[((size_t)(cs << 10) + grow) * 32 + n * 16 + lr]
                            = f2h_bits(uacc[cs][n][jj]);
                    }
        }
        return;
    }

    if (role == 48){
        #pragma unroll
        for (int q = 0; q < 18; ++q){
            int e = t + q * 512;
            int co  = e / 288;
            int rem = e - co * 288;
            int ci  = rem / 9;
            int tap = rem - ci * 9;
            w2f16[(tap * 32 + co) * 32 + (ci ^ SWZ(co))] = f2h_bits(w2[e]);
        }
        return;
    }

    // ---------------- partial_c role (q = role-32, j in [q*64, q*64+64)) ----
    {
        float* ws_l = reinterpret_cast<float*>(smem);          // 64 f32
        float* ws_r = reinterpret_cast<float*>(smem + 256);    // 64 f32
        float* red  = reinterpret_cast<float*>(smem + 512);    // 512 f32

        const int q  = role - 32;
        const int jb = q * 64;

        // phase 1: w[j] for this chunk (threads 0..63)
        if (t < 64){
            int j = jb + t;
            float sl = 0.f, sr = 0.f;
            #pragma unroll
            for (int b = 0; b < 16; ++b){
                sl += part[b * 1024 + j];
                sr += part[16384 + b * 1024 + j];
            }
            ws_l[t] = sl; ws_r[t] = sr;
        }
        __syncthreads();

        // phase 2: partial dot. thread (h = t>>4, g = t&15) handles 4 j's
        const int h = t >> 4;          // 0..31
        const int g = t & 15;          // 0..15
        const float* wl = W_hopi + (size_t)h * 2048 + jb + g * 4;
        const float* wr = wl + 1024;
        float4 a = *reinterpret_cast<const float4*>(wl);
        float4 b = *reinterpret_cast<const float4*>(wr);
        const float* l = &ws_l[g * 4];
        const float* r = &ws_r[g * 4];
        float s = l[0] * a.x + l[1] * a.y + l[2] * a.z + l[3] * a.w
                + r[0] * b.x + r[1] * b.y + r[2] * b.z + r[3] * b.w;
        red[t] = s;
        __syncthreads();
        if (t < 32){
            float tot = 0.f;
            #pragma unroll
            for (int gg = 0; gg < 16; ++gg) tot += red[t * 16 + gg];
            cpart[q * 32 + t] = tot;
        }
    }
}

// ---------------------------------------------------------------------------
// K2b: kfin_kernel. 1 block x 512. c[h] = b_hopi[h] + sum_q cpart[q][h];
// Kp from unrolled w1 taps (all inputs L2-hot).
// ---------------------------------------------------------------------------
__global__ __launch_bounds__(512) void kfin_kernel(
    const float* __restrict__ b_hopi, const float* __restrict__ w1,
    const float* __restrict__ b1, const float* __restrict__ cpart,
    float* __restrict__ Kp)
{
    __shared__ float cvs[32];
    __shared__ float w1s[9216];
    const int t = threadIdx.x;

    #pragma unroll
    for (int q = 0; q < 5; ++q){
        int i4 = t + q * 512;
        if (i4 < 2304)
            *reinterpret_cast<float4*>(&w1s[i4 * 4]) =
                *reinterpret_cast<const float4*>(w1 + i4 * 4);
    }
    if (t < 32){
        float tot = b_hopi[t];
        #pragma unroll
        for (int q = 0; q < 16; ++q) tot += cpart[q * 32 + t];
        cvs[t] = tot;
    }
    __syncthreads();
    for (int e = t; e < 288; e += 512){
        int co  = e & 31;
        int cse = e >> 5;
        int yc  = cse / 3, xc = cse - yc * 3;
        float sum = b1[co];
        for (int ci = 0; ci < 32; ++ci){
            const float* wp = &w1s[co * 288 + ci * 9];
            float t00 = wp[0], t01 = wp[1], t02 = wp[2];
            float t10 = wp[3], t11 = wp[4], t12 = wp[5];
            float t20 = wp[6], t21 = wp[7], t22 = wp[8];
            float r0, r1, r2;
            if (xc == 0){ r0 = t00+t01+t02; r1 = t10+t11+t12; r2 = t20+t21+t22; }
            else if (xc == 1){ r0 = t01+t02; r1 = t11+t12; r2 = t21+t22; }
            else { r0 = t00+t01; r1 = t10+t11; r2 = t20+t21; }
            float wsum = (yc == 0) ? (r0+r1+r2) : ((yc == 1) ? (r1+r2) : (r0+r1));
            sum = fmaf(cvs[ci], wsum, sum);
        }
        Kp[cse * 32 + co] = sum;
    }
}

// ---------------------------------------------------------------------------
// K3: stage ys = relu(U+V+K') (interior fast path in packed f16), wB by uint4
// copy of prepacked w2f16, then conv2+relu+conv3 on f16 MFMA. LDS = 39,168 B.
// block 512, grid 64x64. (round-16 verbatim)
// ---------------------------------------------------------------------------
__global__ __launch_bounds__(512) void conv_kernel(
    const short* __restrict__ U16, const short* __restrict__ V16,
    const float* __restrict__ Kp, const short* __restrict__ w2f16,
    const float* __restrict__ b2,
    const float* __restrict__ w3, const float* __restrict__ b3,
    float* __restrict__ outp)
{
    __shared__ __attribute__((aligned(16))) short ys[18 * 18 * 32];
    __shared__ __attribute__((aligned(16))) short wB[9 * 32 * 32];

    const int t    = threadIdx.x;
    const int oy0  = blockIdx.y * 16;
    const int ox0  = blockIdx.x * 16;
    const int wid  = t >> 6;
    const int lane = t & 63;
    const int lr   = lane & 15;
    const int lg   = lane >> 4;

    {
        const uint4* src = reinterpret_cast<const uint4*>(w2f16);
        uint4* dst = reinterpret_cast<uint4*>(wB);
        #pragma unroll
        for (int e = t; e < 1152; e += 512)
            dst[e] = src[e];
    }
    const bool interior = (blockIdx.x >= 1) & (blockIdx.x <= 62) &
                          (blockIdx.y >= 1) & (blockIdx.y <= 62);
    if (interior){
        const int cp = (t & 7) * 4;
        half4 k00;
        {
            float4 kf = *reinterpret_cast<const float4*>(&Kp[cp]);
            k00[0] = (_Float16)kf.x; k00[1] = (_Float16)kf.y;
            k00[2] = (_Float16)kf.z; k00[3] = (_Float16)kf.w;
        }
        #pragma unroll
        for (int pass = 0; pass < 6; ++pass){
            int idx = t + pass * 512;
            if (idx < 2592){
                int po  = idx >> 3;
                int ryo = po / 18;
                int rxo = po - ryo * 18;
                int gy = oy0 - 1 + ryo, gx = ox0 - 1 + rxo;
                half4 u = *reinterpret_cast<const half4*>(&U16[gy * 32 + cp]);
                half4 v = *reinterpret_cast<const half4*>(&V16[gx * 32 + cp]);
                half4 r = u + v + k00;
                #pragma unroll
                for (int e = 0; e < 4; ++e)
                    r[e] = r[e] > (_Float16)0.f ? r[e] : (_Float16)0.f;
                *reinterpret_cast<half4*>(&ys[po * 32 + (cp ^ SWZ(rxo))]) = r;
            }
        }
    } else {
        #pragma unroll
        for (int pass = 0; pass < 6; ++pass){
            int idx = t + pass * 512;
            if (idx < 2592){
                int po  = idx >> 3;
                int cp  = (idx & 7) * 4;
                int ryo = po / 18;
                int rxo = po - ryo * 18;
                int gy = oy0 - 1 + ryo, gx = ox0 - 1 + rxo;
                half4 h = {(_Float16)0.f, (_Float16)0.f, (_Float16)0.f, (_Float16)0.f};
                if ((unsigned)gy < 1024u && (unsigned)gx < 1024u){
                    int yc = (gy == 0) ? 1 : ((gy == 1023) ? 2 : 0);
                    int xc = (gx == 0) ? 1 : ((gx == 1023) ? 2 : 0);
                    half4 u = *reinterpret_cast<const half4*>(
                        &U16[((size_t)(xc << 10) + gy) * 32 + cp]);
                    half4 v = *reinterpret_cast<const half4*>(
                        &V16[((size_t)(yc << 10) + gx) * 32 + cp]);
                    float4 k = *reinterpret_cast<const float4*>(&Kp[(yc * 3 + xc) * 32 + cp]);
                    h[0] = (_Float16)fmaxf((float)u[0] + (float)v[0] + k.x, 0.f);
                    h[1] = (_Float16)fmaxf((float)u[1] + (float)v[1] + k.y, 0.f);
                    h[2] = (_Float16)fmaxf((float)u[2] + (float)v[2] + k.z, 0.f);
                    h[3] = (_Float16)fmaxf((float)u[3] + (float)v[3] + k.w, 0.f);
                }
                *reinterpret_cast<half4*>(&ys[po * 32 + (cp ^ SWZ(rxo))]) = h;
            }
        }
    }
    __syncthreads();

    {
        half8 Bf[2][9];
        float bias[2], w3v[2];
        #pragma unroll
        for (int n = 0; n < 2; ++n){
            int co = n * 16 + lr;
            bias[n] = b2[co];
            w3v[n]  = w3[co];
            #pragma unroll
            for (int tap = 0; tap < 9; ++tap)
                Bf[n][tap] = *reinterpret_cast<const half8*>(
                    &wB[(tap * 32 + co) * 32 + ((lg * 8) ^ SWZ(co))]);
        }
        const float b3v = b3[0];
        for (int s = wid; s < 16; s += 8){
            int p  = s * 16 + lr;
            int ry = p >> 4;
            int rx = p & 15;
            f32x4 acc0 = {0.f, 0.f, 0.f, 0.f};
            f32x4 acc1 = {0.f, 0.f, 0.f, 0.f};
            #pragma unroll
            for (int tap = 0; tap < 9; ++tap){
                const int dy = tap / 3, dx = tap - (tap / 3) * 3;
                int pix = (ry + dy) * 18 + rx + dx;
                half8 A = *reinterpret_cast<const half8*>(
                    &ys[pix * 32 + ((lg * 8) ^ SWZ(rx + dx))]);
                acc0 = __builtin_amdgcn_mfma_f32_16x16x32_f16(A, Bf[0][tap], acc0, 0, 0, 0);
                acc1 = __builtin_amdgcn_mfma_f32_16x16x32_f16(A, Bf[1][tap], acc1, 0, 0, 0);
            }
            float part[4];
            #pragma unroll
            for (int j = 0; j < 4; ++j)
                part[j] = w3v[0] * fmaxf(acc0[j] + bias[0], 0.f)
                        + w3v[1] * fmaxf(acc1[j] + bias[1], 0.f);
            #pragma unroll
            for (int m = 1; m < 16; m <<= 1)
                #pragma unroll
                for (int j = 0; j < 4; ++j)
                    part[j] += __shfl_xor(part[j], m);
            if (lr == 0){
                float4 o = make_float4(part[0] + b3v, part[1] + b3v,
                                       part[2] + b3v, part[3] + b3v);
                *reinterpret_cast<float4*>(outp + (size_t)(oy0 + s) * 1024 + ox0 + lg * 4) = o;
            }
        }
    }
}

// ---------------------------------------------------------------------------
extern "C" void kernel_launch(void* const* d_in, const int* in_sizes, int n_in,
                              void* d_out, int out_size, void* d_ws, size_t ws_size,
                              hipStream_t stream)
{
    const float* lig_nf = (const float*)d_in[0];
    const float* lig_ef = (const float*)d_in[1];
    const float* rec_nf = (const float*)d_in[3];
    const float* rec_ef = (const float*)d_in[4];
    const float* Wn     = (const float*)d_in[6];
    const float* bn     = (const float*)d_in[7];
    const float* We     = (const float*)d_in[8];
    const float* be     = (const float*)d_in[9];
    const float* W_hopi = (const float*)d_in[12];
    const float* b_hopi = (const float*)d_in[13];
    const float* w1     = (const float*)d_in[14];
    const float* b1     = (const float*)d_in[15];
    const float* w2     = (const float*)d_in[16];
    const float* b2     = (const float*)d_in[17];
    const float* w3     = (const float*)d_in[18];
    const float* b3     = (const float*)d_in[19];
    float* outp = (float*)d_out;

    float* part  = (float*)d_ws;                              // [2][16][1024] f32
    short* Pw    = (short*)((char*)d_ws + 131072);            // [2][1024][32] f16
    float* cpart = (float*)((char*)d_ws + 262144);            // [16][32] f32
    float* Kp    = (float*)((char*)d_ws + 393216);            // 3*3*32 f32
    short* U16   = (short*)((char*)d_ws + 394368);            // 3*1024*32 f16
    short* V16   = (short*)((char*)d_ws + 590976);            // 3*1024*32 f16
    short* w2f16 = (short*)((char*)d_ws + 787584);            // 9216 f16 swizzled

    dim3 g1(8, 16, 2);
    gnn_kernel<<<g1, 512, 0, stream>>>(lig_nf, lig_ef, rec_nf, rec_ef,
                                       Wn, We, bn, be, W_hopi, part, Pw);
    pp2_kernel<<<49, 512, 0, stream>>>(W_hopi, w1, w2, part, Pw,
                                       cpart, U16, V16, w2f16);
    kfin_kernel<<<1, 512, 0, stream>>>(b_hopi, w1, b1, cpart, Kp);
    dim3 g3(64, 64);
    conv_kernel<<<g3, 512, 0, stream>>>(U16, V16, Kp, w2f16, b2, w3, b3, outp);
}